// Round 19
// baseline (328.290 us; speedup 1.0000x reference)
//
#include <hip/hip_runtime.h>
#include <math.h>

#define N 2048
#define D 48
#define K 16
#define TILE 64
#define NT 32                 // tiles per dimension
#define NBLK (NT * (NT + 1) / 2)   // 528 upper-triangular tiles

// FROZEN numerics contract (validated r18, absmax = 1 bf16 ulp):
//   s = (q0 + q2) + q1   (plain, pinned)  — XLA SLP horizontal tree
//   g = fma(x2,y2, fma(x1,y1, fl(x0*y0))) — Eigen-FMA ascending chain
//   t1 = fl(s_n + s_m); d2 = fl(t1 - 2g); dist = d2>0 ? sqrt(d2) : 0
// out[n][m] == out[m][n] bitwise (adds/muls commute) -> triangular compute.

__global__ __launch_bounds__(256, 4)
void volt_tri(const float* __restrict__ vct, const float* __restrict__ posnum,
              float* __restrict__ out) {
#pragma clang fp contract(off)
    __shared__ float4 AB[2][K * TILE];   // [set][k*64 + r] = {x0,x1,x2,s}

    const int tid = threadIdx.x;

    // decode upper-triangular tile (by <= bx) from blockIdx
    int t = blockIdx.x;
    int by = (int)(32.5 - sqrt(32.5 * 32.5 - 2.0 * (double)t));
    if (by < 0) by = 0;
    while (32 * (by + 1) - ((by + 1) * by) / 2 <= t) ++by;
    while (32 * by - (by * (by - 1)) / 2 > t) --by;
    const int bx = by + (t - (32 * by - (by * (by - 1)) / 2));

    const int row0 = by * TILE, col0 = bx * TILE;

    const float tau = posnum[0];
    const float lam = posnum[1];
    const float t2 = tau * tau;   // fl(tau^2)
    const float l2 = lam * lam;   // fl(lam^2)

    // stage both point sets: 2 sets x 64 rows x 16 chunks = 2048 float4 tasks
    for (int it = 0; it < 8; ++it) {
        int task = tid + 256 * it;
        int set = task >> 10;
        int rk = task & 1023;
        int r = rk & 63, k = rk >> 6;
        int base = ((set ? col0 : row0) + r) * D + k * 3;
        float x0 = vct[base + 0];
        float x1 = vct[base + 1];
        float x2 = vct[base + 2];
        float q0 = x0 * x0, q1 = x1 * x1, q2 = x2 * x2;
        asm volatile("" : "+v"(q0), "+v"(q1), "+v"(q2));
        float s02 = q0 + q2;
        asm volatile("" : "+v"(s02));
        float s = s02 + q1;                    // (q0+q2)+q1, pinned plain
        AB[set][k * TILE + r] = make_float4(x0, x1, x2, s);
    }
    __syncthreads();

    const int tx = tid & 15;
    const int ty = tid >> 4;

    // out = 1 + G/Pd, descending-k recurrence (== ref's weighted cumprod sum
    // to ~2e-6 relative):  G_k = l2*(Pd_{k+1} + G_{k+1});  Pd_k = Pd_{k+1}*den_k
    float G[4][4], Pd[4][4];
#pragma unroll
    for (int i = 0; i < 4; ++i)
#pragma unroll
        for (int j = 0; j < 4; ++j) { G[i][j] = 0.0f; Pd[i][j] = 1.0f; }

#pragma unroll
    for (int k = K - 1; k >= 0; --k) {
        float4 a[4], b[4];
#pragma unroll
        for (int i = 0; i < 4; ++i) a[i] = AB[0][k * TILE + ty + 16 * i];
#pragma unroll
        for (int j = 0; j < 4; ++j) b[j] = AB[1][k * TILE + tx + 16 * j];
#pragma unroll
        for (int i = 0; i < 4; ++i)
#pragma unroll
            for (int j = 0; j < 4; ++j) {
                // FROZEN distance path
                float g = __builtin_fmaf(a[i].z, b[j].z,
                          __builtin_fmaf(a[i].y, b[j].y, a[i].x * b[j].x));
                float t1 = a[i].w + b[j].w;
                float d2 = t1 - 2.0f * g;
                float dist = (d2 > 0.0f) ? __builtin_amdgcn_sqrtf(d2) : 0.0f;
                float ip  = 1.0f - dist;
                float den = 1.0f - t2 * ip;
                G[i][j]  = l2 * (Pd[i][j] + G[i][j]);
                Pd[i][j] = Pd[i][j] * den;
            }
    }

    const bool offdiag = (bx != by);
#pragma unroll
    for (int i = 0; i < 4; ++i) {
        int r = ty + 16 * i;
#pragma unroll
        for (int j = 0; j < 4; ++j) {
            int c = tx + 16 * j;
            float v = 1.0f + G[i][j] * __builtin_amdgcn_rcpf(Pd[i][j]);
            out[(size_t)(row0 + r) * N + (col0 + c)] = v;
            if (offdiag)
                out[(size_t)(col0 + c) * N + (row0 + r)] = v;  // exact mirror
        }
    }
}

extern "C" void kernel_launch(void* const* d_in, const int* in_sizes, int n_in,
                              void* d_out, int out_size, void* d_ws, size_t ws_size,
                              hipStream_t stream) {
    const float* vct    = (const float*)d_in[0];
    const float* posnum = (const float*)d_in[1];
    float* out          = (float*)d_out;

    volt_tri<<<NBLK, 256, 0, stream>>>(vct, posnum, out);
}

// Round 20
// 28.589 us; speedup vs baseline: 11.4833x; 11.4833x over previous
//
#include <hip/hip_runtime.h>
#include <math.h>

#define N 2048
#define D 48
#define K 16
#define TILE 64
#define NT 32                      // tiles per dimension
#define NBLK (NT * (NT + 1) / 2)   // 528 upper-triangular tiles

// FROZEN numerics contract (validated r18, absmax = 1 bf16 ulp):
//   s = (q0 + q2) + q1   (plain, pinned)  — XLA SLP horizontal tree
//   g = fma(x2,y2, fma(x1,y1, fl(x0*y0))) — Eigen-FMA ascending chain
//   t1 = fl(s_n + s_m); d2 = fl(t1 - 2g); dist = d2>0 ? sqrt(d2) : 0
// out[n][m] == out[m][n] bitwise -> triangular compute + LDS-transposed
// coalesced mirror store (r19 lesson: raw scatter = 30x write amplification).

__global__ __launch_bounds__(256, 4)
void volt_tri(const float* __restrict__ vct, const float* __restrict__ posnum,
              float* __restrict__ out) {
#pragma clang fp contract(off)
    __shared__ float4 AB[2][K * TILE];            // 32 KB staging
    float* T = reinterpret_cast<float*>(AB);      // reused as T[64][66] (16.9 KB)

    const int tid = threadIdx.x;

    // decode upper-triangular tile (by <= bx) from blockIdx
    int t = blockIdx.x;
    int by = 0;
    while (32 * (by + 1) - ((by + 1) * by) / 2 <= t) ++by;
    const int bx = by + (t - (32 * by - (by * (by - 1)) / 2));

    const int row0 = by * TILE, col0 = bx * TILE;

    const float tau = posnum[0];
    const float lam = posnum[1];
    const float t2 = tau * tau;   // fl(tau^2)
    const float l2 = lam * lam;   // fl(lam^2)

    // stage both point sets: 2 sets x 64 rows x 16 chunks = 2048 float4 tasks
    for (int it = 0; it < 8; ++it) {
        int task = tid + 256 * it;
        int set = task >> 10;
        int rk = task & 1023;
        int r = rk & 63, k = rk >> 6;
        int base = ((set ? col0 : row0) + r) * D + k * 3;
        float x0 = vct[base + 0];
        float x1 = vct[base + 1];
        float x2 = vct[base + 2];
        float q0 = x0 * x0, q1 = x1 * x1, q2 = x2 * x2;
        asm volatile("" : "+v"(q0), "+v"(q1), "+v"(q2));
        float s02 = q0 + q2;
        asm volatile("" : "+v"(s02));
        float s = s02 + q1;                    // (q0+q2)+q1, pinned plain
        AB[set][k * TILE + r] = make_float4(x0, x1, x2, s);
    }
    __syncthreads();

    const int tx = tid & 15;
    const int ty = tid >> 4;

    // out = 1 + G/Pd, descending-k recurrence (== ref's weighted cumprod sum
    // to ~2e-6 relative):  G_k = l2*(Pd_{k+1} + G_{k+1});  Pd_k = Pd_{k+1}*den_k
    float G[4][4], Pd[4][4];
#pragma unroll
    for (int i = 0; i < 4; ++i)
#pragma unroll
        for (int j = 0; j < 4; ++j) { G[i][j] = 0.0f; Pd[i][j] = 1.0f; }

#pragma unroll
    for (int k = K - 1; k >= 0; --k) {
        float4 a[4], b[4];
#pragma unroll
        for (int i = 0; i < 4; ++i) a[i] = AB[0][k * TILE + ty + 16 * i];
#pragma unroll
        for (int j = 0; j < 4; ++j) b[j] = AB[1][k * TILE + tx + 16 * j];
#pragma unroll
        for (int i = 0; i < 4; ++i)
#pragma unroll
            for (int j = 0; j < 4; ++j) {
                // FROZEN distance path
                float g = __builtin_fmaf(a[i].z, b[j].z,
                          __builtin_fmaf(a[i].y, b[j].y, a[i].x * b[j].x));
                float t1 = a[i].w + b[j].w;
                float d2 = t1 - 2.0f * g;
                float dist = (d2 > 0.0f) ? __builtin_amdgcn_sqrtf(d2) : 0.0f;
                float ip  = 1.0f - dist;
                float den = 1.0f - t2 * ip;
                G[i][j]  = l2 * (Pd[i][j] + G[i][j]);
                Pd[i][j] = Pd[i][j] * den;
            }
    }

    // finalize values
    float val[4][4];
#pragma unroll
    for (int i = 0; i < 4; ++i)
#pragma unroll
        for (int j = 0; j < 4; ++j)
            val[i][j] = 1.0f + G[i][j] * __builtin_amdgcn_rcpf(Pd[i][j]);

    // direct store (coalesced: lanes vary tx -> consecutive columns)
#pragma unroll
    for (int i = 0; i < 4; ++i) {
        int r = ty + 16 * i;
#pragma unroll
        for (int j = 0; j < 4; ++j)
            out[(size_t)(row0 + r) * N + (col0 + tx + 16 * j)] = val[i][j];
    }

    if (bx != by) {
        __syncthreads();   // all AB reads done; safe to reuse as T
        // transpose through LDS: T[c][r] = v(r,c), stride 66 (<=2-way alias)
#pragma unroll
        for (int i = 0; i < 4; ++i)
#pragma unroll
            for (int j = 0; j < 4; ++j)
                T[(tx + 16 * j) * 66 + (ty + 16 * i)] = val[i][j];
        __syncthreads();
        // coalesced mirror store: row (col0+rr), cols row0..row0+63
#pragma unroll
        for (int i = 0; i < 4; ++i) {
            int rr = ty + 16 * i;
#pragma unroll
            for (int j = 0; j < 4; ++j) {
                int cc = tx + 16 * j;
                out[(size_t)(col0 + rr) * N + (row0 + cc)] = T[rr * 66 + cc];
            }
        }
    }
}

extern "C" void kernel_launch(void* const* d_in, const int* in_sizes, int n_in,
                              void* d_out, int out_size, void* d_ws, size_t ws_size,
                              hipStream_t stream) {
    const float* vct    = (const float*)d_in[0];
    const float* posnum = (const float*)d_in[1];
    float* out          = (float*)d_out;

    volt_tri<<<NBLK, 256, 0, stream>>>(vct, posnum, out);
}

// Round 21
// 24.936 us; speedup vs baseline: 13.1654x; 1.1465x over previous
//
#include <hip/hip_runtime.h>
#include <math.h>

#define N 2048
#define D 48
#define K 16
#define TILE 32
#define NT (N / TILE)              // 64 tiles per dimension
#define NBLK (NT * (NT + 1) / 2)   // 2080 upper-triangular tiles

// FROZEN numerics contract (validated r18, absmax = 1 bf16 ulp):
//   s = (q0 + q2) + q1   (plain, pinned)  — XLA SLP horizontal tree
//   g = fma(x2,y2, fma(x1,y1, fl(x0*y0))) — Eigen-FMA ascending chain
//   t1 = fl(s_n + s_m); d2 = fl(t1 - 2g); dist = d2>0 ? sqrt(d2) : 0
//   ip = fl(1-dist); den = fl(1 - fl(t2*ip))
// out[n][m] == out[m][n] bitwise -> triangular compute; mirror via LDS
// transpose (r19 lesson: raw scatter = 30x write amplification).
// r20 lesson: 528 blocks = 2.06/CU -> stragglers + low occupancy; TILE=32
// gives 2080 blocks (8.1/CU) and 8 co-resident blocks/CU.

__global__ __launch_bounds__(256, 8)
void volt_tri(const float* __restrict__ vct, const float* __restrict__ posnum,
              float* __restrict__ out) {
#pragma clang fp contract(off)
    __shared__ float4 AB[2][K * TILE];            // 16 KB staging
    float* T = reinterpret_cast<float*>(AB);      // reused as T[32][33]

    const int tid = threadIdx.x;

    // decode upper-triangular tile (by <= bx): offset(y) = y*NT - y(y-1)/2
    int t = blockIdx.x;
    int by = 0;
    while ((by + 1) * NT - ((by + 1) * by) / 2 <= t) ++by;
    const int bx = by + (t - (by * NT - (by * (by - 1)) / 2));

    const int row0 = by * TILE, col0 = bx * TILE;

    const float tau = posnum[0];
    const float lam = posnum[1];
    const float t2 = tau * tau;   // fl(tau^2)
    const float l2 = lam * lam;   // fl(lam^2)

    // stage both point sets: 2 sets x 32 rows x 16 chunks = 1024 float4 tasks
    for (int it = 0; it < 4; ++it) {
        int task = tid + 256 * it;
        int set = task >> 9;
        int rk = task & 511;
        int r = rk & 31, k = rk >> 5;
        int base = ((set ? col0 : row0) + r) * D + k * 3;
        float x0 = vct[base + 0];
        float x1 = vct[base + 1];
        float x2 = vct[base + 2];
        float q0 = x0 * x0, q1 = x1 * x1, q2 = x2 * x2;
        asm volatile("" : "+v"(q0), "+v"(q1), "+v"(q2));
        float s02 = q0 + q2;
        asm volatile("" : "+v"(s02));
        float s = s02 + q1;                    // (q0+q2)+q1, pinned plain
        AB[set][k * TILE + r] = make_float4(x0, x1, x2, s);
    }
    __syncthreads();

    const int tx = tid & 15;
    const int ty = tid >> 4;

    // out = 1 + G/Pd, descending-k recurrence (== ref's weighted cumprod sum
    // to ~2e-6 relative):  G_k = l2*(Pd_{k+1} + G_{k+1});  Pd_k = Pd_{k+1}*den_k
    float G[2][2], Pd[2][2];
#pragma unroll
    for (int i = 0; i < 2; ++i)
#pragma unroll
        for (int j = 0; j < 2; ++j) { G[i][j] = 0.0f; Pd[i][j] = 1.0f; }

#pragma unroll
    for (int k = K - 1; k >= 0; --k) {
        float4 a[2], b[2];
#pragma unroll
        for (int i = 0; i < 2; ++i) a[i] = AB[0][k * TILE + ty + 16 * i];
#pragma unroll
        for (int j = 0; j < 2; ++j) b[j] = AB[1][k * TILE + tx + 16 * j];
#pragma unroll
        for (int i = 0; i < 2; ++i)
#pragma unroll
            for (int j = 0; j < 2; ++j) {
                // FROZEN distance path
                float g = __builtin_fmaf(a[i].z, b[j].z,
                          __builtin_fmaf(a[i].y, b[j].y, a[i].x * b[j].x));
                float t1 = a[i].w + b[j].w;
                float d2 = t1 - 2.0f * g;
                float dist = (d2 > 0.0f) ? __builtin_amdgcn_sqrtf(d2) : 0.0f;
                float ip  = 1.0f - dist;
                float den = 1.0f - t2 * ip;
                G[i][j]  = l2 * (Pd[i][j] + G[i][j]);
                Pd[i][j] = Pd[i][j] * den;
            }
    }

    // finalize values
    float val[2][2];
#pragma unroll
    for (int i = 0; i < 2; ++i)
#pragma unroll
        for (int j = 0; j < 2; ++j)
            val[i][j] = 1.0f + G[i][j] * __builtin_amdgcn_rcpf(Pd[i][j]);

    // direct store (coalesced: lanes vary tx -> consecutive columns)
#pragma unroll
    for (int i = 0; i < 2; ++i) {
        int r = ty + 16 * i;
#pragma unroll
        for (int j = 0; j < 2; ++j)
            out[(size_t)(row0 + r) * N + (col0 + tx + 16 * j)] = val[i][j];
    }

    if (bx != by) {
        __syncthreads();   // all AB reads done; safe to reuse as T
        // transpose through LDS: T[c][r] = v(r,c), stride 33 (odd -> no conflict)
#pragma unroll
        for (int i = 0; i < 2; ++i)
#pragma unroll
            for (int j = 0; j < 2; ++j)
                T[(tx + 16 * j) * 33 + (ty + 16 * i)] = val[i][j];
        __syncthreads();
        // coalesced mirror store: row (col0+rr), cols row0..row0+31
#pragma unroll
        for (int i = 0; i < 2; ++i) {
            int rr = ty + 16 * i;
#pragma unroll
            for (int j = 0; j < 2; ++j) {
                int cc = tx + 16 * j;
                out[(size_t)(col0 + rr) * N + (row0 + cc)] = T[rr * 33 + cc];
            }
        }
    }
}

extern "C" void kernel_launch(void* const* d_in, const int* in_sizes, int n_in,
                              void* d_out, int out_size, void* d_ws, size_t ws_size,
                              hipStream_t stream) {
    const float* vct    = (const float*)d_in[0];
    const float* posnum = (const float*)d_in[1];
    float* out          = (float*)d_out;

    volt_tri<<<NBLK, 256, 0, stream>>>(vct, posnum, out);
}